// Round 1
// 618.064 us; speedup vs baseline: 1.1166x; 1.1166x over previous
//
#include <hip/hip_runtime.h>
#include <stdint.h>

#define B_  8
#define L_  512
#define E_  256
#define H_  128
#define W_  128
#define NH_ 8
#define HD_ 32

typedef unsigned short ushort_t;
typedef __attribute__((ext_vector_type(8))) short bf16x8;
typedef __attribute__((ext_vector_type(4))) float f32x4;

__device__ __forceinline__ float bf2f(ushort_t u) {
    union { unsigned int i; float f; } x;
    x.i = ((unsigned int)u) << 16;
    return x.f;
}
__device__ __forceinline__ ushort_t f2bf(float f) {
    union { float f; unsigned int i; } x;
    x.f = f;
    unsigned int r = x.i + 0x7FFFu + ((x.i >> 16) & 1u);
    return (ushort_t)(r >> 16);
}

// ---------------- mean reductions (mean is linear; project after) --------------
__global__ __launch_bounds__(256) void mean_h_kernel(const float* __restrict__ kr,
                                                     float* __restrict__ out) {
    int i = blockIdx.x * 256 + threadIdx.x;     // (b,w,e)
    int e = i & (E_ - 1);
    int w = (i >> 8) & (W_ - 1);
    int b = i >> 15;
    const float* p = kr + ((size_t)b * H_ * W_ + w) * E_ + e;
    float s = 0.f;
    for (int h = 0; h < H_; ++h) s += p[(size_t)h * W_ * E_];
    out[i] = s * (1.0f / H_);
}
__global__ __launch_bounds__(256) void mean_w_kernel(const float* __restrict__ kc,
                                                     float* __restrict__ out) {
    int i = blockIdx.x * 256 + threadIdx.x;     // (b,h,e)
    int e = i & (E_ - 1);
    int h = (i >> 8) & (H_ - 1);
    int b = i >> 15;
    const float* p = kc + ((size_t)(b * H_ + h) * W_) * E_ + e;
    float s = 0.f;
    for (int w = 0; w < W_; ++w) s += p[(size_t)w * E_];
    out[i] = s * (1.0f / W_);
}

// ---------------- fp32 tile GEMM (projections):  C = scale*(A @ Wt^T + b) ------
__device__ __forceinline__ void load4f(const float* p, float* v) {
    float4 t = *(const float4*)p;
    v[0] = t.x; v[1] = t.y; v[2] = t.z; v[3] = t.w;
}
__device__ __forceinline__ void store4(float* p, float a, float b, float c, float d) {
    float4 t; t.x = a; t.y = b; t.z = c; t.w = d;
    *(float4*)p = t;
}

__global__ __launch_bounds__(256) void gemm256(const float* __restrict__ A,
                                               const float* __restrict__ Wt,
                                               const float* __restrict__ bias,
                                               float* __restrict__ C, int M, float scale) {
    __shared__ __align__(16) float As[16][64];
    __shared__ __align__(16) float Bs[16][64];
    const int m0 = blockIdx.x * 64;
    const int n0 = blockIdx.y * 64;
    const int tid = threadIdx.x;
    const int lr = tid >> 2;
    const int lk = (tid & 3) << 2;
    const int tx = tid & 15, ty = tid >> 4;
    float acc[4][4] = {{0.f}};

    for (int k0 = 0; k0 < E_; k0 += 16) {
        float av[4], wv[4];
        load4f(A + (size_t)(m0 + lr) * E_ + k0 + lk, av);
        load4f(Wt + (size_t)(n0 + lr) * E_ + k0 + lk, wv);
        As[lk + 0][lr] = av[0]; As[lk + 1][lr] = av[1];
        As[lk + 2][lr] = av[2]; As[lk + 3][lr] = av[3];
        Bs[lk + 0][lr] = wv[0]; Bs[lk + 1][lr] = wv[1];
        Bs[lk + 2][lr] = wv[2]; Bs[lk + 3][lr] = wv[3];
        __syncthreads();
#pragma unroll
        for (int k = 0; k < 16; ++k) {
            float a[4], b[4];
            load4f(&As[k][ty << 2], a);
            load4f(&Bs[k][tx << 2], b);
#pragma unroll
            for (int i = 0; i < 4; ++i)
#pragma unroll
                for (int j = 0; j < 4; ++j) acc[i][j] += a[i] * b[j];
        }
        __syncthreads();
    }
    float bv[4];
    load4f(bias + n0 + (tx << 2), bv);
#pragma unroll
    for (int i = 0; i < 4; ++i) {
        float* cp = C + (size_t)(m0 + (ty << 2) + i) * E_ + n0 + (tx << 2);
        store4(cp, scale * (acc[i][0] + bv[0]), scale * (acc[i][1] + bv[1]),
                   scale * (acc[i][2] + bv[2]), scale * (acc[i][3] + bv[3]));
    }
}

// ---------------- W_v -> bf16 ---------------------------------------------------
__global__ __launch_bounds__(256) void wconv_kernel(const float* __restrict__ w,
                                                    ushort_t* __restrict__ wbf) {
    int i = (blockIdx.x * 256 + threadIdx.x) * 4;
    float4 f = *(const float4*)(w + i);
    ushort4 u;
    u.x = f2bf(f.x); u.y = f2bf(f.y); u.z = f2bf(f.z); u.w = f2bf(f.w);
    *(ushort4*)(wbf + i) = u;
}

// ---------------- value projection, MFMA bf16, transposed output ---------------
// v_t[b][e][m],  m = h*128+w.  SWAPPED operands vs previous version:
// A-op = value rows (m), B-op = W rows (e)  =>  D[row=quad*4+reg -> m][col=lc -> e]
// Each lane's 4 acc regs are 4 CONSECUTIVE m at fixed e -> aligned ushort4 (8B)
// stores; the 4 quads of each lc form a contiguous 32B run.  Waves split e
// (64 e per wave); W-fragment loads drop 128 -> 32 per thread, stores 64 -> 16.
#define KP_ 264
__global__ __launch_bounds__(256) void vproj_mfma(const float* __restrict__ Ag,
                                                  const ushort_t* __restrict__ Wbf,
                                                  const float* __restrict__ bias,
                                                  ushort_t* __restrict__ v_t) {
    __shared__ ushort_t A_lds[64 * KP_];         // 33.7 KB
    const int m0 = blockIdx.x * 64;
    const int tid = threadIdx.x, lane = tid & 63, wv = tid >> 6;
    const int quad = lane >> 4, lc = lane & 15;
    {   // stage 64 value rows fp32 -> bf16
        int r = tid >> 2, kq = (tid & 3) * 64;
        const float* sa = Ag + (size_t)(m0 + r) * 256 + kq;
        ushort_t* da = A_lds + r * KP_ + kq;
#pragma unroll
        for (int j = 0; j < 16; ++j) {
            float4 f = *(const float4*)(sa + j * 4);
            ushort4 u;
            u.x = f2bf(f.x); u.y = f2bf(f.y); u.z = f2bf(f.z); u.w = f2bf(f.w);
            *(ushort4*)(da + j * 4) = u;
        }
    }
    __syncthreads();

    f32x4 acc[4][4];    // [mtile t][etile et]
#pragma unroll
    for (int t = 0; t < 4; ++t)
#pragma unroll
        for (int et = 0; et < 4; ++et) {
            acc[t][et][0] = 0.f; acc[t][et][1] = 0.f;
            acc[t][et][2] = 0.f; acc[t][et][3] = 0.f;
        }

    // W fragment base for this wave's e-range: rows wv*64 + et*16 + lc
    const ushort_t* wrow = Wbf + (size_t)(wv * 64 + lc) * 256 + quad * 8;

#pragma unroll
    for (int kc = 0; kc < 8; ++kc) {
        bf16x8 vf[4];
#pragma unroll
        for (int t = 0; t < 4; ++t)
            vf[t] = *(const bf16x8*)(A_lds + (t * 16 + lc) * KP_ + kc * 32 + quad * 8);
#pragma unroll
        for (int et = 0; et < 4; ++et) {
            bf16x8 wf = *(const bf16x8*)(wrow + (size_t)(et * 16) * 256 + kc * 32);
#pragma unroll
            for (int t = 0; t < 4; ++t)
                acc[t][et] = __builtin_amdgcn_mfma_f32_16x16x32_bf16(vf[t], wf, acc[t][et], 0, 0, 0);
        }
    }

    const int b = m0 >> 14;
    const int ml = m0 & 16383;
    ushort_t* vtb = v_t + (size_t)b * 4194304 + ml + quad * 4;
#pragma unroll
    for (int et = 0; et < 4; ++et) {
        const int e = wv * 64 + et * 16 + lc;
        const float bv = bias[e];
        ushort_t* vte = vtb + (size_t)e * 16384;
#pragma unroll
        for (int t = 0; t < 4; ++t) {
            ushort4 u;
            u.x = f2bf(acc[t][et][0] + bv);
            u.y = f2bf(acc[t][et][1] + bv);
            u.z = f2bf(acc[t][et][2] + bv);
            u.w = f2bf(acc[t][et][3] + bv);
            *(ushort4*)(vte + t * 16) = u;
        }
    }
}

// ---------------- row scores, tiled: 32 l x 128 w per block --------------------
// a[bn][l][w] = softmax_w(q_row . k_row)
__global__ __launch_bounds__(256) void scores_row(const float* __restrict__ q,
                                                  const float* __restrict__ k,
                                                  float* __restrict__ a) {
    const int lt = blockIdx.x, bn = blockIdx.y;
    const int n = bn & 7, b = bn >> 3;
    const int tid = threadIdx.x;
    __shared__ float ks[128][36];
    {   // stage k slice [128][32]
        int r = tid >> 1, c16 = (tid & 1) * 16;
        const float* src = k + ((size_t)b * 128 + r) * 256 + n * 32 + c16;
#pragma unroll
        for (int j = 0; j < 4; ++j) {
            float4 f = *(const float4*)(src + j * 4);
            ks[r][c16 + j * 4 + 0] = f.x; ks[r][c16 + j * 4 + 1] = f.y;
            ks[r][c16 + j * 4 + 2] = f.z; ks[r][c16 + j * 4 + 3] = f.w;
        }
    }
    const int ll = tid >> 3, wq = tid & 7;      // w = 8*j + wq
    float4 q4r[8];
    {
        const float* qp = q + ((size_t)b * 512 + lt * 32 + ll) * 256 + n * 32;
#pragma unroll
        for (int c4 = 0; c4 < 8; ++c4) q4r[c4] = *(const float4*)(qp + c4 * 4);
    }
    __syncthreads();
    float dots[16];
#pragma unroll
    for (int j = 0; j < 16; ++j) dots[j] = 0.f;
#pragma unroll
    for (int c4 = 0; c4 < 8; ++c4) {
        float4 q4 = q4r[c4];
#pragma unroll
        for (int j = 0; j < 16; ++j) {
            float4 k4 = *(const float4*)&ks[j * 8 + wq][c4 * 4];
            dots[j] += q4.x * k4.x + q4.y * k4.y + q4.z * k4.z + q4.w * k4.w;
        }
    }
    float mx = dots[0];
#pragma unroll
    for (int j = 1; j < 16; ++j) mx = fmaxf(mx, dots[j]);
    for (int d = 1; d < 8; d <<= 1) mx = fmaxf(mx, __shfl_xor(mx, d, 64));
    float ex[16], sm = 0.f;
#pragma unroll
    for (int j = 0; j < 16; ++j) { ex[j] = __expf(dots[j] - mx); sm += ex[j]; }
    for (int d = 1; d < 8; d <<= 1) sm += __shfl_xor(sm, d, 64);
    float inv = 1.0f / sm;
    float* ap = a + ((size_t)bn * 512 + lt * 32 + ll) * 128 + wq;
#pragma unroll
    for (int j = 0; j < 16; ++j) ap[j * 8] = ex[j] * inv;
}

// ---------------- col scores, tiled + transposed output ------------------------
// ac_t[bn][h][l] = softmax_h(q_col . k_col)
__global__ __launch_bounds__(256) void scores_col(const float* __restrict__ q,
                                                  const float* __restrict__ k,
                                                  float* __restrict__ ac_t) {
    const int lt = blockIdx.x, bn = blockIdx.y;
    const int n = bn & 7, b = bn >> 3;
    const int tid = threadIdx.x;
    __shared__ float qs[32][36];
    __shared__ float sc[128][33];
    __shared__ float mxr[8][32], smr[8][32], fin[2][32];
    {   // stage q tile [32][32]
        int r = tid >> 3, c4 = (tid & 7) * 4;
        float4 f = *(const float4*)(q + ((size_t)b * 512 + lt * 32 + r) * 256 + n * 32 + c4);
        qs[r][c4 + 0] = f.x; qs[r][c4 + 1] = f.y; qs[r][c4 + 2] = f.z; qs[r][c4 + 3] = f.w;
    }
    const int h = tid >> 1, lq = tid & 1;
    float4 kk[8];
    {
        const float* kp = k + ((size_t)b * 128 + h) * 256 + n * 32;
#pragma unroll
        for (int c4 = 0; c4 < 8; ++c4) kk[c4] = *(const float4*)(kp + c4 * 4);
    }
    __syncthreads();
    float dots[16];
#pragma unroll
    for (int j = 0; j < 16; ++j) dots[j] = 0.f;
#pragma unroll
    for (int c4 = 0; c4 < 8; ++c4) {
        float4 k4 = kk[c4];
#pragma unroll
        for (int j = 0; j < 16; ++j) {
            float4 q4 = *(const float4*)&qs[j * 2 + lq][c4 * 4];
            dots[j] += k4.x * q4.x + k4.y * q4.y + k4.z * q4.z + k4.w * q4.w;
        }
    }
#pragma unroll
    for (int j = 0; j < 16; ++j) sc[h][j * 2 + lq] = dots[j];
    __syncthreads();
    {   // per-l max over h (8 segs x 16)
        int lcol = tid & 31, seg = tid >> 5;
        float m = -3.0e38f;
#pragma unroll
        for (int i = 0; i < 16; ++i) m = fmaxf(m, sc[seg * 16 + i][lcol]);
        mxr[seg][lcol] = m;
    }
    __syncthreads();
    if (tid < 32) {
        float m = mxr[0][tid];
#pragma unroll
        for (int s = 1; s < 8; ++s) m = fmaxf(m, mxr[s][tid]);
        fin[0][tid] = m;
    }
    __syncthreads();
    {
        int lcol = tid & 31, seg = tid >> 5;
        float m = fin[0][lcol], s = 0.f;
#pragma unroll
        for (int i = 0; i < 16; ++i) s += __expf(sc[seg * 16 + i][lcol] - m);
        smr[seg][lcol] = s;
    }
    __syncthreads();
    if (tid < 32) {
        float t = 0.f;
#pragma unroll
        for (int s = 1; s < 8; ++s) t += smr[s][tid];
        fin[1][tid] = 1.0f / (t + smr[0][tid]);
    }
    __syncthreads();
    {   // write [h][l], contiguous in l
        const int lh = (tid & 1) * 16;
        float* op = ac_t + ((size_t)bn * 128 + h) * 512 + lt * 32;
#pragma unroll
        for (int j4 = 0; j4 < 4; ++j4) {
            int l0 = lh + j4 * 4;
            float4 o;
            o.x = __expf(sc[h][l0 + 0] - fin[0][l0 + 0]) * fin[1][l0 + 0];
            o.y = __expf(sc[h][l0 + 1] - fin[0][l0 + 1]) * fin[1][l0 + 1];
            o.z = __expf(sc[h][l0 + 2] - fin[0][l0 + 2]) * fin[1][l0 + 2];
            o.w = __expf(sc[h][l0 + 3] - fin[0][l0 + 3]) * fin[1][l0 + 3];
            *(float4*)(op + l0) = o;
        }
    }
}

// ---------------- fused axial attention core, MFMA bf16 ------------------------
#define ARP 136
#define VBP 136
__global__ __launch_bounds__(256) void core_mfma(const float* __restrict__ a_row,
                                                 const float* __restrict__ ac_t,
                                                 const ushort_t* __restrict__ v_t,
                                                 float* __restrict__ attn) {
    __shared__ ushort_t ar_lds[64 * ARP];          // 17.4 KB
    __shared__ ushort_t vb_lds[2][64 * VBP];       // 2 x 17.4 KB (2 h per buffer)
    const int blk = blockIdx.x;                    // lt*64 + bn: siblings share XCD
    const int lt = blk >> 6, bn = blk & 63;
    const int n = bn & 7, b = bn >> 3;
    const int tid = threadIdx.x, lane = tid & 63, wv = tid >> 6;
    const int quad = lane >> 4, lc = lane & 15;

    {   // a_row -> bf16 LDS
        const size_t abase = ((size_t)bn * L_ + lt * 64) * 128;
        int r = tid >> 2, wq = (tid & 3) * 32;
        const float* src = a_row + abase + (size_t)r * 128 + wq;
        ushort_t* dst = ar_lds + r * ARP + wq;
#pragma unroll
        for (int j = 0; j < 8; ++j) {
            float4 f = *(const float4*)(src + j * 4);
            ushort4 u;
            u.x = f2bf(f.x); u.y = f2bf(f.y); u.z = f2bf(f.z); u.w = f2bf(f.w);
            *(ushort4*)(dst + j * 4) = u;
        }
    }
    const float* act = ac_t + (size_t)bn * 65536 + lt * 64 + wv * 16 + quad * 4;
    const ushort_t* vtb = v_t + (size_t)b * 4194304 + (size_t)(n * 32) * 16384;
    const int sc_ = tid >> 3, sw = (tid & 7) * 16;
#define STAGE2(hh, bu)                                                             \
    {                                                                              \
        const ushort_t* s0 = vtb + (size_t)sc_ * 16384 + (hh) * 128 + sw;          \
        ushort_t* d0 = vb_lds[bu] + sc_ * VBP + sw;                                \
        *(uint4*)d0 = *(const uint4*)s0;                                           \
        *(uint4*)(d0 + 8) = *(const uint4*)(s0 + 8);                               \
        const ushort_t* s1 = s0 + 128;                                             \
        ushort_t* d1 = d0 + 32 * VBP;                                              \
        *(uint4*)d1 = *(const uint4*)s1;                                           \
        *(uint4*)(d1 + 8) = *(const uint4*)(s1 + 8);                               \
    }
    STAGE2(0, 0);
    __syncthreads();                    // ar + pair0 visible
    bf16x8 A[4];
#pragma unroll
    for (int kc = 0; kc < 4; ++kc)
        A[kc] = *(const bf16x8*)(ar_lds + (wv * 16 + lc) * ARP + kc * 32 + quad * 8);

    f32x4 acc0 = {0.f,0.f,0.f,0.f}, acc1 = {0.f,0.f,0.f,0.f};
    for (int hh = 0; hh < 128; hh += 2) {
        const int buf = (hh >> 1) & 1;
        if (hh) __syncthreads();        // pair(hh) visible; pair(hh-2) fully consumed
        if (hh + 2 < 128) STAGE2(hh + 2, buf ^ 1);
        float4 av0 = *(const float4*)(act + (size_t)hh * 512);
        float4 av1 = *(const float4*)(act + (size_t)(hh + 1) * 512);
        const ushort_t* vb0 = vb_lds[buf];
        const ushort_t* vb1 = vb_lds[buf] + 32 * VBP;
        f32x4 t0 = {0.f,0.f,0.f,0.f}, t1 = {0.f,0.f,0.f,0.f};
        f32x4 u0 = {0.f,0.f,0.f,0.f}, u1 = {0.f,0.f,0.f,0.f};
#pragma unroll
        for (int kc = 0; kc < 4; ++kc) {
            const int ko = kc * 32 + quad * 8;
            bf16x8 b0 = *(const bf16x8*)(vb0 + lc * VBP + ko);
            bf16x8 b1 = *(const bf16x8*)(vb0 + (16 + lc) * VBP + ko);
            bf16x8 c0 = *(const bf16x8*)(vb1 + lc * VBP + ko);
            bf16x8 c1 = *(const bf16x8*)(vb1 + (16 + lc) * VBP + ko);
            t0 = __builtin_amdgcn_mfma_f32_16x16x32_bf16(A[kc], b0, t0, 0, 0, 0);
            t1 = __builtin_amdgcn_mfma_f32_16x16x32_bf16(A[kc], b1, t1, 0, 0, 0);
            u0 = __builtin_amdgcn_mfma_f32_16x16x32_bf16(A[kc], c0, u0, 0, 0, 0);
            u1 = __builtin_amdgcn_mfma_f32_16x16x32_bf16(A[kc], c1, u1, 0, 0, 0);
        }
        acc0[0] += av0.x * t0[0] + av1.x * u0[0]; acc1[0] += av0.x * t1[0] + av1.x * u1[0];
        acc0[1] += av0.y * t0[1] + av1.y * u0[1]; acc1[1] += av0.y * t1[1] + av1.y * u1[1];
        acc0[2] += av0.z * t0[2] + av1.z * u0[2]; acc1[2] += av0.z * t1[2] + av1.z * u1[2];
        acc0[3] += av0.w * t0[3] + av1.w * u0[3]; acc1[3] += av0.w * t1[3] + av1.w * u1[3];
    }
    const int row0 = wv * 16 + quad * 4;
#pragma unroll
    for (int r = 0; r < 4; ++r) {
        size_t o = ((size_t)(lt * 64 + row0 + r) * B_ + b) * E_ + n * HD_ + lc;
        attn[o] = acc0[r];
        attn[o + 16] = acc1[r];
    }
#undef STAGE2
}

// ---------------- launch --------------------------------------------------------
extern "C" void kernel_launch(void* const* d_in, const int* in_sizes, int n_in,
                              void* d_out, int out_size, void* d_ws, size_t ws_size,
                              hipStream_t stream) {
    const float* query_row = (const float*)d_in[0];
    const float* query_col = (const float*)d_in[1];
    const float* key_row   = (const float*)d_in[2];
    const float* key_col   = (const float*)d_in[3];
    const float* value     = (const float*)d_in[4];
    const float* ipw       = (const float*)d_in[5];
    const float* ipb       = (const float*)d_in[6];
    const float* opw       = (const float*)d_in[7];
    const float* opb       = (const float*)d_in[8];
    float* out = (float*)d_out;

    char* ws = (char*)d_ws;
    float* q_row_s = (float*)ws;  ws += (size_t)4096 * 256 * 4;
    float* q_col_s = (float*)ws;  ws += (size_t)4096 * 256 * 4;
    float* krm     = (float*)ws;  ws += (size_t)262144 * 4;
    float* kcm     = (float*)ws;  ws += (size_t)262144 * 4;
    float* k_row   = (float*)ws;  ws += (size_t)262144 * 4;
    float* k_col   = (float*)ws;  ws += (size_t)262144 * 4;
    ushort_t* v_t  = (ushort_t*)ws; ws += (size_t)33554432 * 2;   // [B][256][16384]
    float* a_row   = (float*)ws;  ws += (size_t)4194304 * 4;      // [bn][l][w]
    float* ac_t    = (float*)ws;  ws += (size_t)4194304 * 4;      // [bn][h][l]
    float* attn    = (float*)ws;  ws += (size_t)4096 * 256 * 4;
    ushort_t* wbf  = (ushort_t*)ws; ws += (size_t)65536 * 2;

    const float scale = 0.17677669529663687f;   // HD^-0.5

    mean_h_kernel<<<1024, 256, 0, stream>>>(key_row, krm);
    mean_w_kernel<<<1024, 256, 0, stream>>>(key_col, kcm);
    wconv_kernel<<<64, 256, 0, stream>>>(ipw + 4 * 65536, wbf);

    gemm256<<<dim3(64, 4), 256, 0, stream>>>(query_row, ipw + 0 * 65536, ipb + 0,    q_row_s, 4096, scale);
    gemm256<<<dim3(64, 4), 256, 0, stream>>>(query_col, ipw + 1 * 65536, ipb + 256,  q_col_s, 4096, scale);
    gemm256<<<dim3(16, 4), 256, 0, stream>>>(krm,       ipw + 2 * 65536, ipb + 512,  k_row,   1024, 1.0f);
    gemm256<<<dim3(16, 4), 256, 0, stream>>>(kcm,       ipw + 3 * 65536, ipb + 768,  k_col,   1024, 1.0f);

    vproj_mfma<<<2048, 256, 0, stream>>>(value, wbf, ipb + 1024, v_t);

    scores_row<<<dim3(16, 64), 256, 0, stream>>>(q_row_s, k_row, a_row);
    scores_col<<<dim3(16, 64), 256, 0, stream>>>(q_col_s, k_col, ac_t);

    core_mfma<<<512, 256, 0, stream>>>(a_row, ac_t, v_t, attn);

    gemm256<<<dim3(64, 4), 256, 0, stream>>>(attn, opw, opb, out, 4096, 1.0f);
}

// Round 2
// 595.013 us; speedup vs baseline: 1.1599x; 1.0387x over previous
//
#include <hip/hip_runtime.h>
#include <stdint.h>

#define B_  8
#define L_  512
#define E_  256
#define H_  128
#define W_  128
#define NH_ 8
#define HD_ 32

typedef unsigned short ushort_t;
typedef __attribute__((ext_vector_type(8))) short bf16x8;
typedef __attribute__((ext_vector_type(4))) float f32x4;

__device__ __forceinline__ float bf2f(ushort_t u) {
    union { unsigned int i; float f; } x;
    x.i = ((unsigned int)u) << 16;
    return x.f;
}
__device__ __forceinline__ ushort_t f2bf(float f) {
    union { float f; unsigned int i; } x;
    x.f = f;
    unsigned int r = x.i + 0x7FFFu + ((x.i >> 16) & 1u);
    return (ushort_t)(r >> 16);
}

// ---------------- mean reductions (mean is linear; project after) --------------
__global__ __launch_bounds__(256) void mean_h_kernel(const float* __restrict__ kr,
                                                     float* __restrict__ out) {
    int i = blockIdx.x * 256 + threadIdx.x;     // (b,w,e)
    int e = i & (E_ - 1);
    int w = (i >> 8) & (W_ - 1);
    int b = i >> 15;
    const float* p = kr + ((size_t)b * H_ * W_ + w) * E_ + e;
    float s = 0.f;
#pragma unroll 8
    for (int h = 0; h < H_; ++h) s += p[(size_t)h * W_ * E_];
    out[i] = s * (1.0f / H_);
}
__global__ __launch_bounds__(256) void mean_w_kernel(const float* __restrict__ kc,
                                                     float* __restrict__ out) {
    int i = blockIdx.x * 256 + threadIdx.x;     // (b,h,e)
    int e = i & (E_ - 1);
    int h = (i >> 8) & (H_ - 1);
    int b = i >> 15;
    const float* p = kc + ((size_t)(b * H_ + h) * W_) * E_ + e;
    float s = 0.f;
#pragma unroll 8
    for (int w = 0; w < W_; ++w) s += p[(size_t)w * E_];
    out[i] = s * (1.0f / W_);
}

// ---------------- fp32 tile GEMM (projections):  C = scale*(A @ Wt^T + b) ------
__device__ __forceinline__ void load4f(const float* p, float* v) {
    float4 t = *(const float4*)p;
    v[0] = t.x; v[1] = t.y; v[2] = t.z; v[3] = t.w;
}
__device__ __forceinline__ void store4(float* p, float a, float b, float c, float d) {
    float4 t; t.x = a; t.y = b; t.z = c; t.w = d;
    *(float4*)p = t;
}

__global__ __launch_bounds__(256) void gemm256(const float* __restrict__ A,
                                               const float* __restrict__ Wt,
                                               const float* __restrict__ bias,
                                               float* __restrict__ C, int M, float scale) {
    __shared__ __align__(16) float As[16][64];
    __shared__ __align__(16) float Bs[16][64];
    const int m0 = blockIdx.x * 64;
    const int n0 = blockIdx.y * 64;
    const int tid = threadIdx.x;
    const int lr = tid >> 2;
    const int lk = (tid & 3) << 2;
    const int tx = tid & 15, ty = tid >> 4;
    float acc[4][4] = {{0.f}};

    for (int k0 = 0; k0 < E_; k0 += 16) {
        float av[4], wv[4];
        load4f(A + (size_t)(m0 + lr) * E_ + k0 + lk, av);
        load4f(Wt + (size_t)(n0 + lr) * E_ + k0 + lk, wv);
        As[lk + 0][lr] = av[0]; As[lk + 1][lr] = av[1];
        As[lk + 2][lr] = av[2]; As[lk + 3][lr] = av[3];
        Bs[lk + 0][lr] = wv[0]; Bs[lk + 1][lr] = wv[1];
        Bs[lk + 2][lr] = wv[2]; Bs[lk + 3][lr] = wv[3];
        __syncthreads();
#pragma unroll
        for (int k = 0; k < 16; ++k) {
            float a[4], b[4];
            load4f(&As[k][ty << 2], a);
            load4f(&Bs[k][tx << 2], b);
#pragma unroll
            for (int i = 0; i < 4; ++i)
#pragma unroll
                for (int j = 0; j < 4; ++j) acc[i][j] += a[i] * b[j];
        }
        __syncthreads();
    }
    float bv[4];
    load4f(bias + n0 + (tx << 2), bv);
#pragma unroll
    for (int i = 0; i < 4; ++i) {
        float* cp = C + (size_t)(m0 + (ty << 2) + i) * E_ + n0 + (tx << 2);
        store4(cp, scale * (acc[i][0] + bv[0]), scale * (acc[i][1] + bv[1]),
                   scale * (acc[i][2] + bv[2]), scale * (acc[i][3] + bv[3]));
    }
}

// ---------------- W_v -> bf16 ---------------------------------------------------
__global__ __launch_bounds__(256) void wconv_kernel(const float* __restrict__ w,
                                                    ushort_t* __restrict__ wbf) {
    int i = (blockIdx.x * 256 + threadIdx.x) * 4;
    float4 f = *(const float4*)(w + i);
    ushort4 u;
    u.x = f2bf(f.x); u.y = f2bf(f.y); u.z = f2bf(f.z); u.w = f2bf(f.w);
    *(ushort4*)(wbf + i) = u;
}

// ---------------- value projection, MFMA bf16, transposed output ---------------
// v_t[b][e][m],  m = h*128+w.  A-op = value rows (m), B-op = W rows (e):
// D[row=quad*4+reg -> m][col=lc -> e].  Lane's 4 acc regs = 4 consecutive m
// -> aligned ushort4 stores (quads form 32B runs).
// __launch_bounds__(256,3): allow ~170 VGPR so acc[4][4] (64) + wf dbuf (32)
// + vf (16) stay live -> memory-level parallelism (was 76 VGPR = serialized).
#define KP_ 264
__global__ __launch_bounds__(256, 3) void vproj_mfma(const float* __restrict__ Ag,
                                                     const ushort_t* __restrict__ Wbf,
                                                     const float* __restrict__ bias,
                                                     ushort_t* __restrict__ v_t) {
    __shared__ ushort_t A_lds[64 * KP_];         // 33.7 KB
    const int m0 = blockIdx.x * 64;
    const int tid = threadIdx.x, lane = tid & 63, wv = tid >> 6;
    const int quad = lane >> 4, lc = lane & 15;
    {   // stage 64 value rows fp32 -> bf16
        int r = tid >> 2, kq = (tid & 3) * 64;
        const float* sa = Ag + (size_t)(m0 + r) * 256 + kq;
        ushort_t* da = A_lds + r * KP_ + kq;
#pragma unroll
        for (int j = 0; j < 16; ++j) {
            float4 f = *(const float4*)(sa + j * 4);
            ushort4 u;
            u.x = f2bf(f.x); u.y = f2bf(f.y); u.z = f2bf(f.z); u.w = f2bf(f.w);
            *(ushort4*)(da + j * 4) = u;
        }
    }
    __syncthreads();

    f32x4 acc[4][4];    // [mtile t][etile et]
#pragma unroll
    for (int t = 0; t < 4; ++t)
#pragma unroll
        for (int et = 0; et < 4; ++et) {
            acc[t][et][0] = 0.f; acc[t][et][1] = 0.f;
            acc[t][et][2] = 0.f; acc[t][et][3] = 0.f;
        }

    // W fragment base for this wave's e-range: rows wv*64 + et*16 + lc
    const ushort_t* wrow = Wbf + (size_t)(wv * 64 + lc) * 256 + quad * 8;

    bf16x8 wf[4], wn[4];
#pragma unroll
    for (int et = 0; et < 4; ++et)
        wf[et] = *(const bf16x8*)(wrow + (size_t)(et * 16) * 256);

#pragma unroll
    for (int kc = 0; kc < 8; ++kc) {
        bf16x8 vf[4];
#pragma unroll
        for (int t = 0; t < 4; ++t)
            vf[t] = *(const bf16x8*)(A_lds + (t * 16 + lc) * KP_ + kc * 32 + quad * 8);
        if (kc < 7) {
#pragma unroll
            for (int et = 0; et < 4; ++et)
                wn[et] = *(const bf16x8*)(wrow + (size_t)(et * 16) * 256 + (kc + 1) * 32);
        }
#pragma unroll
        for (int et = 0; et < 4; ++et)
#pragma unroll
            for (int t = 0; t < 4; ++t)
                acc[t][et] = __builtin_amdgcn_mfma_f32_16x16x32_bf16(vf[t], wf[et], acc[t][et], 0, 0, 0);
#pragma unroll
        for (int et = 0; et < 4; ++et) wf[et] = wn[et];
    }

    const int b = m0 >> 14;
    const int ml = m0 & 16383;
    ushort_t* vtb = v_t + (size_t)b * 4194304 + ml + quad * 4;
#pragma unroll
    for (int et = 0; et < 4; ++et) {
        const int e = wv * 64 + et * 16 + lc;
        const float bv = bias[e];
        ushort_t* vte = vtb + (size_t)e * 16384;
#pragma unroll
        for (int t = 0; t < 4; ++t) {
            ushort4 u;
            u.x = f2bf(acc[t][et][0] + bv);
            u.y = f2bf(acc[t][et][1] + bv);
            u.z = f2bf(acc[t][et][2] + bv);
            u.w = f2bf(acc[t][et][3] + bv);
            *(ushort4*)(vte + t * 16) = u;
        }
    }
}

// ---------------- row scores, tiled: 32 l x 128 w per block --------------------
// a[bn][l][w] = softmax_w(q_row . k_row)
__global__ __launch_bounds__(256) void scores_row(const float* __restrict__ q,
                                                  const float* __restrict__ k,
                                                  float* __restrict__ a) {
    const int lt = blockIdx.x, bn = blockIdx.y;
    const int n = bn & 7, b = bn >> 3;
    const int tid = threadIdx.x;
    __shared__ float ks[128][36];
    {   // stage k slice [128][32]
        int r = tid >> 1, c16 = (tid & 1) * 16;
        const float* src = k + ((size_t)b * 128 + r) * 256 + n * 32 + c16;
#pragma unroll
        for (int j = 0; j < 4; ++j) {
            float4 f = *(const float4*)(src + j * 4);
            ks[r][c16 + j * 4 + 0] = f.x; ks[r][c16 + j * 4 + 1] = f.y;
            ks[r][c16 + j * 4 + 2] = f.z; ks[r][c16 + j * 4 + 3] = f.w;
        }
    }
    const int ll = tid >> 3, wq = tid & 7;      // w = 8*j + wq
    float4 q4r[8];
    {
        const float* qp = q + ((size_t)b * 512 + lt * 32 + ll) * 256 + n * 32;
#pragma unroll
        for (int c4 = 0; c4 < 8; ++c4) q4r[c4] = *(const float4*)(qp + c4 * 4);
    }
    __syncthreads();
    float dots[16];
#pragma unroll
    for (int j = 0; j < 16; ++j) dots[j] = 0.f;
#pragma unroll
    for (int c4 = 0; c4 < 8; ++c4) {
        float4 q4 = q4r[c4];
#pragma unroll
        for (int j = 0; j < 16; ++j) {
            float4 k4 = *(const float4*)&ks[j * 8 + wq][c4 * 4];
            dots[j] += q4.x * k4.x + q4.y * k4.y + q4.z * k4.z + q4.w * k4.w;
        }
    }
    float mx = dots[0];
#pragma unroll
    for (int j = 1; j < 16; ++j) mx = fmaxf(mx, dots[j]);
    for (int d = 1; d < 8; d <<= 1) mx = fmaxf(mx, __shfl_xor(mx, d, 64));
    float ex[16], sm = 0.f;
#pragma unroll
    for (int j = 0; j < 16; ++j) { ex[j] = __expf(dots[j] - mx); sm += ex[j]; }
    for (int d = 1; d < 8; d <<= 1) sm += __shfl_xor(sm, d, 64);
    float inv = 1.0f / sm;
    float* ap = a + ((size_t)bn * 512 + lt * 32 + ll) * 128 + wq;
#pragma unroll
    for (int j = 0; j < 16; ++j) ap[j * 8] = ex[j] * inv;
}

// ---------------- col scores, tiled + transposed output ------------------------
// ac_t[bn][h][l] = softmax_h(q_col . k_col)
__global__ __launch_bounds__(256) void scores_col(const float* __restrict__ q,
                                                  const float* __restrict__ k,
                                                  float* __restrict__ ac_t) {
    const int lt = blockIdx.x, bn = blockIdx.y;
    const int n = bn & 7, b = bn >> 3;
    const int tid = threadIdx.x;
    __shared__ float qs[32][36];
    __shared__ float sc[128][33];
    __shared__ float mxr[8][32], smr[8][32], fin[2][32];
    {   // stage q tile [32][32]
        int r = tid >> 3, c4 = (tid & 7) * 4;
        float4 f = *(const float4*)(q + ((size_t)b * 512 + lt * 32 + r) * 256 + n * 32 + c4);
        qs[r][c4 + 0] = f.x; qs[r][c4 + 1] = f.y; qs[r][c4 + 2] = f.z; qs[r][c4 + 3] = f.w;
    }
    const int h = tid >> 1, lq = tid & 1;
    float4 kk[8];
    {
        const float* kp = k + ((size_t)b * 128 + h) * 256 + n * 32;
#pragma unroll
        for (int c4 = 0; c4 < 8; ++c4) kk[c4] = *(const float4*)(kp + c4 * 4);
    }
    __syncthreads();
    float dots[16];
#pragma unroll
    for (int j = 0; j < 16; ++j) dots[j] = 0.f;
#pragma unroll
    for (int c4 = 0; c4 < 8; ++c4) {
        float4 k4 = kk[c4];
#pragma unroll
        for (int j = 0; j < 16; ++j) {
            float4 q4 = *(const float4*)&qs[j * 2 + lq][c4 * 4];
            dots[j] += k4.x * q4.x + k4.y * q4.y + k4.z * q4.z + k4.w * q4.w;
        }
    }
#pragma unroll
    for (int j = 0; j < 16; ++j) sc[h][j * 2 + lq] = dots[j];
    __syncthreads();
    {   // per-l max over h (8 segs x 16)
        int lcol = tid & 31, seg = tid >> 5;
        float m = -3.0e38f;
#pragma unroll
        for (int i = 0; i < 16; ++i) m = fmaxf(m, sc[seg * 16 + i][lcol]);
        mxr[seg][lcol] = m;
    }
    __syncthreads();
    if (tid < 32) {
        float m = mxr[0][tid];
#pragma unroll
        for (int s = 1; s < 8; ++s) m = fmaxf(m, mxr[s][tid]);
        fin[0][tid] = m;
    }
    __syncthreads();
    {
        int lcol = tid & 31, seg = tid >> 5;
        float m = fin[0][lcol], s = 0.f;
#pragma unroll
        for (int i = 0; i < 16; ++i) s += __expf(sc[seg * 16 + i][lcol] - m);
        smr[seg][lcol] = s;
    }
    __syncthreads();
    if (tid < 32) {
        float t = 0.f;
#pragma unroll
        for (int s = 1; s < 8; ++s) t += smr[s][tid];
        fin[1][tid] = 1.0f / (t + smr[0][tid]);
    }
    __syncthreads();
    {   // write [h][l], contiguous in l
        const int lh = (tid & 1) * 16;
        float* op = ac_t + ((size_t)bn * 128 + h) * 512 + lt * 32;
#pragma unroll
        for (int j4 = 0; j4 < 4; ++j4) {
            int l0 = lh + j4 * 4;
            float4 o;
            o.x = __expf(sc[h][l0 + 0] - fin[0][l0 + 0]) * fin[1][l0 + 0];
            o.y = __expf(sc[h][l0 + 1] - fin[0][l0 + 1]) * fin[1][l0 + 1];
            o.z = __expf(sc[h][l0 + 2] - fin[0][l0 + 2]) * fin[1][l0 + 2];
            o.w = __expf(sc[h][l0 + 3] - fin[0][l0 + 3]) * fin[1][l0 + 3];
            *(float4*)(op + l0) = o;
        }
    }
}

// ---------------- fused axial attention core, MFMA bf16 ------------------------
// T14 async-STAGE split: issue global loads for pair hh+2 at iteration start,
// run ds_reads + MFMAs on current buffer, write staged regs to LDS + barrier
// at iteration end.  Global latency hides under MFMA instead of being serially
// exposed per iteration.  (256,3): register headroom for the staged uint4s.
#define ARP 136
#define VBP 136
__global__ __launch_bounds__(256, 3) void core_mfma(const float* __restrict__ a_row,
                                                    const float* __restrict__ ac_t,
                                                    const ushort_t* __restrict__ v_t,
                                                    float* __restrict__ attn) {
    __shared__ ushort_t ar_lds[64 * ARP];          // 17.4 KB
    __shared__ ushort_t vb_lds[2][64 * VBP];       // 2 x 17.4 KB (2 h per buffer)
    const int blk = blockIdx.x;                    // lt*64 + bn: siblings share XCD
    const int lt = blk >> 6, bn = blk & 63;
    const int n = bn & 7, b = bn >> 3;
    const int tid = threadIdx.x, lane = tid & 63, wv = tid >> 6;
    const int quad = lane >> 4, lc = lane & 15;

    const ushort_t* vtb = v_t + (size_t)b * 4194304 + (size_t)(n * 32) * 16384;
    const int sc_ = tid >> 3, sw = (tid & 7) * 16;

    // issue pair-0 global loads first: latency hides under a_row conversion
    uint4 p0, p1, p2, p3;
    {
        const ushort_t* s0 = vtb + (size_t)sc_ * 16384 + sw;
        p0 = *(const uint4*)s0;
        p1 = *(const uint4*)(s0 + 8);
        const ushort_t* s1 = s0 + 128;
        p2 = *(const uint4*)s1;
        p3 = *(const uint4*)(s1 + 8);
    }

    {   // a_row -> bf16 LDS
        const size_t abase = ((size_t)bn * L_ + lt * 64) * 128;
        int r = tid >> 2, wq = (tid & 3) * 32;
        const float* src = a_row + abase + (size_t)r * 128 + wq;
        ushort_t* dst = ar_lds + r * ARP + wq;
#pragma unroll
        for (int j = 0; j < 8; ++j) {
            float4 f = *(const float4*)(src + j * 4);
            ushort4 u;
            u.x = f2bf(f.x); u.y = f2bf(f.y); u.z = f2bf(f.z); u.w = f2bf(f.w);
            *(ushort4*)(dst + j * 4) = u;
        }
    }
    {   // write pair 0 into buffer 0
        ushort_t* d0 = vb_lds[0] + sc_ * VBP + sw;
        *(uint4*)d0 = p0;
        *(uint4*)(d0 + 8) = p1;
        ushort_t* d1 = d0 + 32 * VBP;
        *(uint4*)d1 = p2;
        *(uint4*)(d1 + 8) = p3;
    }
    __syncthreads();                    // ar + pair0 visible

    const float* act = ac_t + (size_t)bn * 65536 + lt * 64 + wv * 16 + quad * 4;
    bf16x8 A[4];
#pragma unroll
    for (int kc = 0; kc < 4; ++kc)
        A[kc] = *(const bf16x8*)(ar_lds + (wv * 16 + lc) * ARP + kc * 32 + quad * 8);

    f32x4 acc0 = {0.f,0.f,0.f,0.f}, acc1 = {0.f,0.f,0.f,0.f};
    for (int i = 0; i < 64; ++i) {
        const int hh = i * 2, buf = i & 1;
        if (i < 63) {   // issue next-pair loads (consumed after MFMAs)
            const ushort_t* s0 = vtb + (size_t)sc_ * 16384 + (hh + 2) * 128 + sw;
            p0 = *(const uint4*)s0;
            p1 = *(const uint4*)(s0 + 8);
            const ushort_t* s1 = s0 + 128;
            p2 = *(const uint4*)s1;
            p3 = *(const uint4*)(s1 + 8);
        }
        float4 av0 = *(const float4*)(act + (size_t)hh * 512);
        float4 av1 = *(const float4*)(act + (size_t)(hh + 1) * 512);
        const ushort_t* vb0 = vb_lds[buf];
        const ushort_t* vb1 = vb_lds[buf] + 32 * VBP;
        f32x4 t0 = {0.f,0.f,0.f,0.f}, t1 = {0.f,0.f,0.f,0.f};
        f32x4 u0 = {0.f,0.f,0.f,0.f}, u1 = {0.f,0.f,0.f,0.f};
#pragma unroll
        for (int kc = 0; kc < 4; ++kc) {
            const int ko = kc * 32 + quad * 8;
            bf16x8 b0 = *(const bf16x8*)(vb0 + lc * VBP + ko);
            bf16x8 b1 = *(const bf16x8*)(vb0 + (16 + lc) * VBP + ko);
            bf16x8 c0 = *(const bf16x8*)(vb1 + lc * VBP + ko);
            bf16x8 c1 = *(const bf16x8*)(vb1 + (16 + lc) * VBP + ko);
            t0 = __builtin_amdgcn_mfma_f32_16x16x32_bf16(A[kc], b0, t0, 0, 0, 0);
            t1 = __builtin_amdgcn_mfma_f32_16x16x32_bf16(A[kc], b1, t1, 0, 0, 0);
            u0 = __builtin_amdgcn_mfma_f32_16x16x32_bf16(A[kc], c0, u0, 0, 0, 0);
            u1 = __builtin_amdgcn_mfma_f32_16x16x32_bf16(A[kc], c1, u1, 0, 0, 0);
        }
        acc0[0] += av0.x * t0[0] + av1.x * u0[0]; acc1[0] += av0.x * t1[0] + av1.x * u1[0];
        acc0[1] += av0.y * t0[1] + av1.y * u0[1]; acc1[1] += av0.y * t1[1] + av1.y * u1[1];
        acc0[2] += av0.z * t0[2] + av1.z * u0[2]; acc1[2] += av0.z * t1[2] + av1.z * u1[2];
        acc0[3] += av0.w * t0[3] + av1.w * u0[3]; acc1[3] += av0.w * t1[3] + av1.w * u1[3];
        if (i < 63) {   // write staged pair to the other buffer, then barrier
            ushort_t* d0 = vb_lds[buf ^ 1] + sc_ * VBP + sw;
            *(uint4*)d0 = p0;
            *(uint4*)(d0 + 8) = p1;
            ushort_t* d1 = d0 + 32 * VBP;
            *(uint4*)d1 = p2;
            *(uint4*)(d1 + 8) = p3;
            __syncthreads();
        }
    }
    const int row0 = wv * 16 + quad * 4;
#pragma unroll
    for (int r = 0; r < 4; ++r) {
        size_t o = ((size_t)(lt * 64 + row0 + r) * B_ + b) * E_ + n * HD_ + lc;
        attn[o] = acc0[r];
        attn[o + 16] = acc1[r];
    }
}

// ---------------- launch --------------------------------------------------------
extern "C" void kernel_launch(void* const* d_in, const int* in_sizes, int n_in,
                              void* d_out, int out_size, void* d_ws, size_t ws_size,
                              hipStream_t stream) {
    const float* query_row = (const float*)d_in[0];
    const float* query_col = (const float*)d_in[1];
    const float* key_row   = (const float*)d_in[2];
    const float* key_col   = (const float*)d_in[3];
    const float* value     = (const float*)d_in[4];
    const float* ipw       = (const float*)d_in[5];
    const float* ipb       = (const float*)d_in[6];
    const float* opw       = (const float*)d_in[7];
    const float* opb       = (const float*)d_in[8];
    float* out = (float*)d_out;

    char* ws = (char*)d_ws;
    float* q_row_s = (float*)ws;  ws += (size_t)4096 * 256 * 4;
    float* q_col_s = (float*)ws;  ws += (size_t)4096 * 256 * 4;
    float* krm     = (float*)ws;  ws += (size_t)262144 * 4;
    float* kcm     = (float*)ws;  ws += (size_t)262144 * 4;
    float* k_row   = (float*)ws;  ws += (size_t)262144 * 4;
    float* k_col   = (float*)ws;  ws += (size_t)262144 * 4;
    ushort_t* v_t  = (ushort_t*)ws; ws += (size_t)33554432 * 2;   // [B][256][16384]
    float* a_row   = (float*)ws;  ws += (size_t)4194304 * 4;      // [bn][l][w]
    float* ac_t    = (float*)ws;  ws += (size_t)4194304 * 4;      // [bn][h][l]
    float* attn    = (float*)ws;  ws += (size_t)4096 * 256 * 4;
    ushort_t* wbf  = (ushort_t*)ws; ws += (size_t)65536 * 2;

    const float scale = 0.17677669529663687f;   // HD^-0.5

    mean_h_kernel<<<1024, 256, 0, stream>>>(key_row, krm);
    mean_w_kernel<<<1024, 256, 0, stream>>>(key_col, kcm);
    wconv_kernel<<<64, 256, 0, stream>>>(ipw + 4 * 65536, wbf);

    gemm256<<<dim3(64, 4), 256, 0, stream>>>(query_row, ipw + 0 * 65536, ipb + 0,    q_row_s, 4096, scale);
    gemm256<<<dim3(64, 4), 256, 0, stream>>>(query_col, ipw + 1 * 65536, ipb + 256,  q_col_s, 4096, scale);
    gemm256<<<dim3(16, 4), 256, 0, stream>>>(krm,       ipw + 2 * 65536, ipb + 512,  k_row,   1024, 1.0f);
    gemm256<<<dim3(16, 4), 256, 0, stream>>>(kcm,       ipw + 3 * 65536, ipb + 768,  k_col,   1024, 1.0f);

    vproj_mfma<<<2048, 256, 0, stream>>>(value, wbf, ipb + 1024, v_t);

    scores_row<<<dim3(16, 64), 256, 0, stream>>>(q_row_s, k_row, a_row);
    scores_col<<<dim3(16, 64), 256, 0, stream>>>(q_col_s, k_col, ac_t);

    core_mfma<<<512, 256, 0, stream>>>(a_row, ac_t, v_t, attn);

    gemm256<<<dim3(64, 4), 256, 0, stream>>>(attn, opw, opb, out, 4096, 1.0f);
}

// Round 3
// 589.077 us; speedup vs baseline: 1.1716x; 1.0101x over previous
//
#include <hip/hip_runtime.h>
#include <stdint.h>

#define B_  8
#define L_  512
#define E_  256
#define H_  128
#define W_  128
#define NH_ 8
#define HD_ 32

typedef unsigned short ushort_t;
typedef __attribute__((ext_vector_type(8))) short bf16x8;
typedef __attribute__((ext_vector_type(4))) float f32x4;

__device__ __forceinline__ float bf2f(ushort_t u) {
    union { unsigned int i; float f; } x;
    x.i = ((unsigned int)u) << 16;
    return x.f;
}
__device__ __forceinline__ ushort_t f2bf(float f) {
    union { float f; unsigned int i; } x;
    x.f = f;
    unsigned int r = x.i + 0x7FFFu + ((x.i >> 16) & 1u);
    return (ushort_t)(r >> 16);
}

// ---------------- mean reductions (mean is linear; project after) --------------
__global__ __launch_bounds__(256) void mean_h_kernel(const float* __restrict__ kr,
                                                     float* __restrict__ out) {
    int i = blockIdx.x * 256 + threadIdx.x;     // (b,w,e)
    int e = i & (E_ - 1);
    int w = (i >> 8) & (W_ - 1);
    int b = i >> 15;
    const float* p = kr + ((size_t)b * H_ * W_ + w) * E_ + e;
    float s = 0.f;
#pragma unroll 8
    for (int h = 0; h < H_; ++h) s += p[(size_t)h * W_ * E_];
    out[i] = s * (1.0f / H_);
}
__global__ __launch_bounds__(256) void mean_w_kernel(const float* __restrict__ kc,
                                                     float* __restrict__ out) {
    int i = blockIdx.x * 256 + threadIdx.x;     // (b,h,e)
    int e = i & (E_ - 1);
    int h = (i >> 8) & (H_ - 1);
    int b = i >> 15;
    const float* p = kc + ((size_t)(b * H_ + h) * W_) * E_ + e;
    float s = 0.f;
#pragma unroll 8
    for (int w = 0; w < W_; ++w) s += p[(size_t)w * E_];
    out[i] = s * (1.0f / W_);
}

// ---------------- fp32 tile GEMM (projections):  C = scale*(A @ Wt^T + b) ------
__device__ __forceinline__ void load4f(const float* p, float* v) {
    float4 t = *(const float4*)p;
    v[0] = t.x; v[1] = t.y; v[2] = t.z; v[3] = t.w;
}
__device__ __forceinline__ void store4(float* p, float a, float b, float c, float d) {
    float4 t; t.x = a; t.y = b; t.z = c; t.w = d;
    *(float4*)p = t;
}

__global__ __launch_bounds__(256) void gemm256(const float* __restrict__ A,
                                               const float* __restrict__ Wt,
                                               const float* __restrict__ bias,
                                               float* __restrict__ C, int M, float scale) {
    __shared__ __align__(16) float As[16][64];
    __shared__ __align__(16) float Bs[16][64];
    const int m0 = blockIdx.x * 64;
    const int n0 = blockIdx.y * 64;
    const int tid = threadIdx.x;
    const int lr = tid >> 2;
    const int lk = (tid & 3) << 2;
    const int tx = tid & 15, ty = tid >> 4;
    float acc[4][4] = {{0.f}};

    for (int k0 = 0; k0 < E_; k0 += 16) {
        float av[4], wv[4];
        load4f(A + (size_t)(m0 + lr) * E_ + k0 + lk, av);
        load4f(Wt + (size_t)(n0 + lr) * E_ + k0 + lk, wv);
        As[lk + 0][lr] = av[0]; As[lk + 1][lr] = av[1];
        As[lk + 2][lr] = av[2]; As[lk + 3][lr] = av[3];
        Bs[lk + 0][lr] = wv[0]; Bs[lk + 1][lr] = wv[1];
        Bs[lk + 2][lr] = wv[2]; Bs[lk + 3][lr] = wv[3];
        __syncthreads();
#pragma unroll
        for (int k = 0; k < 16; ++k) {
            float a[4], b[4];
            load4f(&As[k][ty << 2], a);
            load4f(&Bs[k][tx << 2], b);
#pragma unroll
            for (int i = 0; i < 4; ++i)
#pragma unroll
                for (int j = 0; j < 4; ++j) acc[i][j] += a[i] * b[j];
        }
        __syncthreads();
    }
    float bv[4];
    load4f(bias + n0 + (tx << 2), bv);
#pragma unroll
    for (int i = 0; i < 4; ++i) {
        float* cp = C + (size_t)(m0 + (ty << 2) + i) * E_ + n0 + (tx << 2);
        store4(cp, scale * (acc[i][0] + bv[0]), scale * (acc[i][1] + bv[1]),
                   scale * (acc[i][2] + bv[2]), scale * (acc[i][3] + bv[3]));
    }
}

// ---------------- W_v -> bf16 ---------------------------------------------------
__global__ __launch_bounds__(256) void wconv_kernel(const float* __restrict__ w,
                                                    ushort_t* __restrict__ wbf) {
    int i = (blockIdx.x * 256 + threadIdx.x) * 4;
    float4 f = *(const float4*)(w + i);
    ushort4 u;
    u.x = f2bf(f.x); u.y = f2bf(f.y); u.z = f2bf(f.z); u.w = f2bf(f.w);
    *(ushort4*)(wbf + i) = u;
}

// ---------------- value projection, MFMA bf16, transposed output ---------------
// v_t[b][e][m],  m = h*128+w.  A-op = value rows (m), B-op = W rows (e):
// D[row=quad*4+reg -> m][col=lc -> e].  Lane's 4 acc regs = 4 consecutive m.
// (256,4): 64 arch VGPR + 64 AGPR = 128 unified -> 4 waves/SIMD resident
// (was capped at 3 by (256,3)).  Stage uses (tid&3)*4 + j*16 columns:
// 64B-contiguous global reads per quad, LDS write banks {0,2,4,6} (no conflict).
#define KP_ 264
__global__ __launch_bounds__(256, 4) void vproj_mfma(const float* __restrict__ Ag,
                                                     const ushort_t* __restrict__ Wbf,
                                                     const float* __restrict__ bias,
                                                     ushort_t* __restrict__ v_t) {
    __shared__ ushort_t A_lds[64 * KP_];         // 33.7 KB
    const int m0 = blockIdx.x * 64;
    const int tid = threadIdx.x, lane = tid & 63, wv = tid >> 6;
    const int quad = lane >> 4, lc = lane & 15;
    {   // stage 64 value rows fp32 -> bf16
        int r = tid >> 2, c0 = (tid & 3) * 4;
        const float* sa = Ag + (size_t)(m0 + r) * 256 + c0;
        ushort_t* da = A_lds + r * KP_ + c0;
#pragma unroll
        for (int j = 0; j < 16; ++j) {
            float4 f = *(const float4*)(sa + j * 16);
            ushort4 u;
            u.x = f2bf(f.x); u.y = f2bf(f.y); u.z = f2bf(f.z); u.w = f2bf(f.w);
            *(ushort4*)(da + j * 16) = u;
        }
    }
    __syncthreads();

    f32x4 acc[4][4];    // [mtile t][etile et]
#pragma unroll
    for (int t = 0; t < 4; ++t)
#pragma unroll
        for (int et = 0; et < 4; ++et) {
            acc[t][et][0] = 0.f; acc[t][et][1] = 0.f;
            acc[t][et][2] = 0.f; acc[t][et][3] = 0.f;
        }

    // W fragment base for this wave's e-range: rows wv*64 + et*16 + lc
    const ushort_t* wrow = Wbf + (size_t)(wv * 64 + lc) * 256 + quad * 8;

    bf16x8 wf[4], wn[4];
#pragma unroll
    for (int et = 0; et < 4; ++et)
        wf[et] = *(const bf16x8*)(wrow + (size_t)(et * 16) * 256);

#pragma unroll
    for (int kc = 0; kc < 8; ++kc) {
        bf16x8 vf[4];
#pragma unroll
        for (int t = 0; t < 4; ++t)
            vf[t] = *(const bf16x8*)(A_lds + (t * 16 + lc) * KP_ + kc * 32 + quad * 8);
        if (kc < 7) {
#pragma unroll
            for (int et = 0; et < 4; ++et)
                wn[et] = *(const bf16x8*)(wrow + (size_t)(et * 16) * 256 + (kc + 1) * 32);
        }
#pragma unroll
        for (int et = 0; et < 4; ++et)
#pragma unroll
            for (int t = 0; t < 4; ++t)
                acc[t][et] = __builtin_amdgcn_mfma_f32_16x16x32_bf16(vf[t], wf[et], acc[t][et], 0, 0, 0);
#pragma unroll
        for (int et = 0; et < 4; ++et) wf[et] = wn[et];
    }

    const int b = m0 >> 14;
    const int ml = m0 & 16383;
    ushort_t* vtb = v_t + (size_t)b * 4194304 + ml + quad * 4;
#pragma unroll
    for (int et = 0; et < 4; ++et) {
        const int e = wv * 64 + et * 16 + lc;
        const float bv = bias[e];
        ushort_t* vte = vtb + (size_t)e * 16384;
#pragma unroll
        for (int t = 0; t < 4; ++t) {
            ushort4 u;
            u.x = f2bf(acc[t][et][0] + bv);
            u.y = f2bf(acc[t][et][1] + bv);
            u.z = f2bf(acc[t][et][2] + bv);
            u.w = f2bf(acc[t][et][3] + bv);
            *(ushort4*)(vte + t * 16) = u;
        }
    }
}

// ---------------- row scores, tiled: 32 l x 128 w per block --------------------
// a[bn][l][w] = softmax_w(q_row . k_row)
__global__ __launch_bounds__(256) void scores_row(const float* __restrict__ q,
                                                  const float* __restrict__ k,
                                                  float* __restrict__ a) {
    const int lt = blockIdx.x, bn = blockIdx.y;
    const int n = bn & 7, b = bn >> 3;
    const int tid = threadIdx.x;
    __shared__ float ks[128][36];
    {   // stage k slice [128][32]
        int r = tid >> 1, c16 = (tid & 1) * 16;
        const float* src = k + ((size_t)b * 128 + r) * 256 + n * 32 + c16;
#pragma unroll
        for (int j = 0; j < 4; ++j) {
            float4 f = *(const float4*)(src + j * 4);
            ks[r][c16 + j * 4 + 0] = f.x; ks[r][c16 + j * 4 + 1] = f.y;
            ks[r][c16 + j * 4 + 2] = f.z; ks[r][c16 + j * 4 + 3] = f.w;
        }
    }
    const int ll = tid >> 3, wq = tid & 7;      // w = 8*j + wq
    float4 q4r[8];
    {
        const float* qp = q + ((size_t)b * 512 + lt * 32 + ll) * 256 + n * 32;
#pragma unroll
        for (int c4 = 0; c4 < 8; ++c4) q4r[c4] = *(const float4*)(qp + c4 * 4);
    }
    __syncthreads();
    float dots[16];
#pragma unroll
    for (int j = 0; j < 16; ++j) dots[j] = 0.f;
#pragma unroll
    for (int c4 = 0; c4 < 8; ++c4) {
        float4 q4 = q4r[c4];
#pragma unroll
        for (int j = 0; j < 16; ++j) {
            float4 k4 = *(const float4*)&ks[j * 8 + wq][c4 * 4];
            dots[j] += q4.x * k4.x + q4.y * k4.y + q4.z * k4.z + q4.w * k4.w;
        }
    }
    float mx = dots[0];
#pragma unroll
    for (int j = 1; j < 16; ++j) mx = fmaxf(mx, dots[j]);
    for (int d = 1; d < 8; d <<= 1) mx = fmaxf(mx, __shfl_xor(mx, d, 64));
    float ex[16], sm = 0.f;
#pragma unroll
    for (int j = 0; j < 16; ++j) { ex[j] = __expf(dots[j] - mx); sm += ex[j]; }
    for (int d = 1; d < 8; d <<= 1) sm += __shfl_xor(sm, d, 64);
    float inv = 1.0f / sm;
    float* ap = a + ((size_t)bn * 512 + lt * 32 + ll) * 128 + wq;
#pragma unroll
    for (int j = 0; j < 16; ++j) ap[j * 8] = ex[j] * inv;
}

// ---------------- col scores, tiled + transposed output ------------------------
// ac_t[bn][h][l] = softmax_h(q_col . k_col)
__global__ __launch_bounds__(256) void scores_col(const float* __restrict__ q,
                                                  const float* __restrict__ k,
                                                  float* __restrict__ ac_t) {
    const int lt = blockIdx.x, bn = blockIdx.y;
    const int n = bn & 7, b = bn >> 3;
    const int tid = threadIdx.x;
    __shared__ float qs[32][36];
    __shared__ float sc[128][33];
    __shared__ float mxr[8][32], smr[8][32], fin[2][32];
    {   // stage q tile [32][32]
        int r = tid >> 3, c4 = (tid & 7) * 4;
        float4 f = *(const float4*)(q + ((size_t)b * 512 + lt * 32 + r) * 256 + n * 32 + c4);
        qs[r][c4 + 0] = f.x; qs[r][c4 + 1] = f.y; qs[r][c4 + 2] = f.z; qs[r][c4 + 3] = f.w;
    }
    const int h = tid >> 1, lq = tid & 1;
    float4 kk[8];
    {
        const float* kp = k + ((size_t)b * 128 + h) * 256 + n * 32;
#pragma unroll
        for (int c4 = 0; c4 < 8; ++c4) kk[c4] = *(const float4*)(kp + c4 * 4);
    }
    __syncthreads();
    float dots[16];
#pragma unroll
    for (int j = 0; j < 16; ++j) dots[j] = 0.f;
#pragma unroll
    for (int c4 = 0; c4 < 8; ++c4) {
        float4 k4 = kk[c4];
#pragma unroll
        for (int j = 0; j < 16; ++j) {
            float4 q4 = *(const float4*)&qs[j * 2 + lq][c4 * 4];
            dots[j] += k4.x * q4.x + k4.y * q4.y + k4.z * q4.z + k4.w * q4.w;
        }
    }
#pragma unroll
    for (int j = 0; j < 16; ++j) sc[h][j * 2 + lq] = dots[j];
    __syncthreads();
    {   // per-l max over h (8 segs x 16)
        int lcol = tid & 31, seg = tid >> 5;
        float m = -3.0e38f;
#pragma unroll
        for (int i = 0; i < 16; ++i) m = fmaxf(m, sc[seg * 16 + i][lcol]);
        mxr[seg][lcol] = m;
    }
    __syncthreads();
    if (tid < 32) {
        float m = mxr[0][tid];
#pragma unroll
        for (int s = 1; s < 8; ++s) m = fmaxf(m, mxr[s][tid]);
        fin[0][tid] = m;
    }
    __syncthreads();
    {
        int lcol = tid & 31, seg = tid >> 5;
        float m = fin[0][lcol], s = 0.f;
#pragma unroll
        for (int i = 0; i < 16; ++i) s += __expf(sc[seg * 16 + i][lcol] - m);
        smr[seg][lcol] = s;
    }
    __syncthreads();
    if (tid < 32) {
        float t = 0.f;
#pragma unroll
        for (int s = 1; s < 8; ++s) t += smr[s][tid];
        fin[1][tid] = 1.0f / (t + smr[0][tid]);
    }
    __syncthreads();
    {   // write [h][l], contiguous in l
        const int lh = (tid & 1) * 16;
        float* op = ac_t + ((size_t)bn * 128 + h) * 512 + lt * 32;
#pragma unroll
        for (int j4 = 0; j4 < 4; ++j4) {
            int l0 = lh + j4 * 4;
            float4 o;
            o.x = __expf(sc[h][l0 + 0] - fin[0][l0 + 0]) * fin[1][l0 + 0];
            o.y = __expf(sc[h][l0 + 1] - fin[0][l0 + 1]) * fin[1][l0 + 1];
            o.z = __expf(sc[h][l0 + 2] - fin[0][l0 + 2]) * fin[1][l0 + 2];
            o.w = __expf(sc[h][l0 + 3] - fin[0][l0 + 3]) * fin[1][l0 + 3];
            *(float4*)(op + l0) = o;
        }
    }
}

// ---------------- fused axial attention core, MFMA bf16 ------------------------
// 512-thread blocks, 128 l per block (8 waves x 16 l): halves v_t request
// traffic (each (b,n) v-slice read by 4 blocks instead of 8) and doubles
// MFMA per staged byte.  blk = ltg*64 + bn keeps same-bn blocks on one XCD
// (bn%8) for L2 reuse of the 1MB v-slice.  T14 async-STAGE split retained:
// issue next-pair global loads before MFMAs, LDS-write after.
#define ARP 136
#define VBP 136
__global__ __launch_bounds__(512, 2) void core_mfma(const float* __restrict__ a_row,
                                                    const float* __restrict__ ac_t,
                                                    const ushort_t* __restrict__ v_t,
                                                    float* __restrict__ attn) {
    __shared__ ushort_t ar_lds[128 * ARP];         // 34.8 KB
    __shared__ ushort_t vb_lds[2][64 * VBP];       // 2 x 17.4 KB (2 h per buffer)
    const int blk = blockIdx.x;                    // ltg*64 + bn
    const int ltg = blk >> 6, bn = blk & 63;
    const int n = bn & 7, b = bn >> 3;
    const int tid = threadIdx.x, lane = tid & 63, wv = tid >> 6;   // wv 0..7
    const int quad = lane >> 4, lc = lane & 15;

    const ushort_t* vtb = v_t + (size_t)b * 4194304 + (size_t)(n * 32) * 16384;
    const int sc_ = tid >> 4, sw = (tid & 15) * 8;   // e'-row, 16B chunk

    // issue pair-0 global loads first: latency hides under a_row conversion
    uint4 p0, p1;
    {
        const ushort_t* s0 = vtb + (size_t)sc_ * 16384 + sw;
        p0 = *(const uint4*)s0;            // h = 0
        p1 = *(const uint4*)(s0 + 128);    // h = 1
    }

    {   // a_row -> bf16 LDS, 128 rows (bank-friendly column mapping)
        const size_t abase = ((size_t)bn * L_ + ltg * 128) * 128;
        int r = tid >> 2, c0 = (tid & 3) * 4;
        const float* src = a_row + abase + (size_t)r * 128 + c0;
        ushort_t* dst = ar_lds + r * ARP + c0;
#pragma unroll
        for (int j = 0; j < 8; ++j) {
            float4 f = *(const float4*)(src + j * 16);
            ushort4 u;
            u.x = f2bf(f.x); u.y = f2bf(f.y); u.z = f2bf(f.z); u.w = f2bf(f.w);
            *(ushort4*)(dst + j * 16) = u;
        }
    }
    {   // write pair 0 into buffer 0
        ushort_t* d0 = vb_lds[0] + sc_ * VBP + sw;
        *(uint4*)d0 = p0;
        *(uint4*)(d0 + 32 * VBP) = p1;
    }
    __syncthreads();                    // ar + pair0 visible

    const float* act = ac_t + (size_t)bn * 65536 + ltg * 128 + wv * 16 + quad * 4;
    bf16x8 A[4];
#pragma unroll
    for (int kc = 0; kc < 4; ++kc)
        A[kc] = *(const bf16x8*)(ar_lds + (wv * 16 + lc) * ARP + kc * 32 + quad * 8);

    f32x4 acc0 = {0.f,0.f,0.f,0.f}, acc1 = {0.f,0.f,0.f,0.f};
    for (int i = 0; i < 64; ++i) {
        const int hh = i * 2, buf = i & 1;
        if (i < 63) {   // issue next-pair loads (consumed after MFMAs)
            const ushort_t* s0 = vtb + (size_t)sc_ * 16384 + (hh + 2) * 128 + sw;
            p0 = *(const uint4*)s0;
            p1 = *(const uint4*)(s0 + 128);
        }
        float4 av0 = *(const float4*)(act + (size_t)hh * 512);
        float4 av1 = *(const float4*)(act + (size_t)(hh + 1) * 512);
        const ushort_t* vb0 = vb_lds[buf];
        const ushort_t* vb1 = vb_lds[buf] + 32 * VBP;
        f32x4 t0 = {0.f,0.f,0.f,0.f}, t1 = {0.f,0.f,0.f,0.f};
        f32x4 u0 = {0.f,0.f,0.f,0.f}, u1 = {0.f,0.f,0.f,0.f};
#pragma unroll
        for (int kc = 0; kc < 4; ++kc) {
            const int ko = kc * 32 + quad * 8;
            bf16x8 b0 = *(const bf16x8*)(vb0 + lc * VBP + ko);
            bf16x8 b1 = *(const bf16x8*)(vb0 + (16 + lc) * VBP + ko);
            bf16x8 c0 = *(const bf16x8*)(vb1 + lc * VBP + ko);
            bf16x8 c1 = *(const bf16x8*)(vb1 + (16 + lc) * VBP + ko);
            t0 = __builtin_amdgcn_mfma_f32_16x16x32_bf16(A[kc], b0, t0, 0, 0, 0);
            t1 = __builtin_amdgcn_mfma_f32_16x16x32_bf16(A[kc], b1, t1, 0, 0, 0);
            u0 = __builtin_amdgcn_mfma_f32_16x16x32_bf16(A[kc], c0, u0, 0, 0, 0);
            u1 = __builtin_amdgcn_mfma_f32_16x16x32_bf16(A[kc], c1, u1, 0, 0, 0);
        }
        acc0[0] += av0.x * t0[0] + av1.x * u0[0]; acc1[0] += av0.x * t1[0] + av1.x * u1[0];
        acc0[1] += av0.y * t0[1] + av1.y * u0[1]; acc1[1] += av0.y * t1[1] + av1.y * u1[1];
        acc0[2] += av0.z * t0[2] + av1.z * u0[2]; acc1[2] += av0.z * t1[2] + av1.z * u1[2];
        acc0[3] += av0.w * t0[3] + av1.w * u0[3]; acc1[3] += av0.w * t1[3] + av1.w * u1[3];
        if (i < 63) {   // write staged pair to the other buffer, then barrier
            ushort_t* d0 = vb_lds[buf ^ 1] + sc_ * VBP + sw;
            *(uint4*)d0 = p0;
            *(uint4*)(d0 + 32 * VBP) = p1;
            __syncthreads();
        }
    }
    const int row0 = wv * 16 + quad * 4;
#pragma unroll
    for (int r = 0; r < 4; ++r) {
        size_t o = ((size_t)(ltg * 128 + row0 + r) * B_ + b) * E_ + n * HD_ + lc;
        attn[o] = acc0[r];
        attn[o + 16] = acc1[r];
    }
}

// ---------------- launch --------------------------------------------------------
extern "C" void kernel_launch(void* const* d_in, const int* in_sizes, int n_in,
                              void* d_out, int out_size, void* d_ws, size_t ws_size,
                              hipStream_t stream) {
    const float* query_row = (const float*)d_in[0];
    const float* query_col = (const float*)d_in[1];
    const float* key_row   = (const float*)d_in[2];
    const float* key_col   = (const float*)d_in[3];
    const float* value     = (const float*)d_in[4];
    const float* ipw       = (const float*)d_in[5];
    const float* ipb       = (const float*)d_in[6];
    const float* opw       = (const float*)d_in[7];
    const float* opb       = (const float*)d_in[8];
    float* out = (float*)d_out;

    char* ws = (char*)d_ws;
    float* q_row_s = (float*)ws;  ws += (size_t)4096 * 256 * 4;
    float* q_col_s = (float*)ws;  ws += (size_t)4096 * 256 * 4;
    float* krm     = (float*)ws;  ws += (size_t)262144 * 4;
    float* kcm     = (float*)ws;  ws += (size_t)262144 * 4;
    float* k_row   = (float*)ws;  ws += (size_t)262144 * 4;
    float* k_col   = (float*)ws;  ws += (size_t)262144 * 4;
    ushort_t* v_t  = (ushort_t*)ws; ws += (size_t)33554432 * 2;   // [B][256][16384]
    float* a_row   = (float*)ws;  ws += (size_t)4194304 * 4;      // [bn][l][w]
    float* ac_t    = (float*)ws;  ws += (size_t)4194304 * 4;      // [bn][h][l]
    float* attn    = (float*)ws;  ws += (size_t)4096 * 256 * 4;
    ushort_t* wbf  = (ushort_t*)ws; ws += (size_t)65536 * 2;

    const float scale = 0.17677669529663687f;   // HD^-0.5

    mean_h_kernel<<<1024, 256, 0, stream>>>(key_row, krm);
    mean_w_kernel<<<1024, 256, 0, stream>>>(key_col, kcm);
    wconv_kernel<<<64, 256, 0, stream>>>(ipw + 4 * 65536, wbf);

    gemm256<<<dim3(64, 4), 256, 0, stream>>>(query_row, ipw + 0 * 65536, ipb + 0,    q_row_s, 4096, scale);
    gemm256<<<dim3(64, 4), 256, 0, stream>>>(query_col, ipw + 1 * 65536, ipb + 256,  q_col_s, 4096, scale);
    gemm256<<<dim3(16, 4), 256, 0, stream>>>(krm,       ipw + 2 * 65536, ipb + 512,  k_row,   1024, 1.0f);
    gemm256<<<dim3(16, 4), 256, 0, stream>>>(kcm,       ipw + 3 * 65536, ipb + 768,  k_col,   1024, 1.0f);

    vproj_mfma<<<2048, 256, 0, stream>>>(value, wbf, ipb + 1024, v_t);

    scores_row<<<dim3(16, 64), 256, 0, stream>>>(q_row_s, k_row, a_row);
    scores_col<<<dim3(16, 64), 256, 0, stream>>>(q_col_s, k_col, ac_t);

    core_mfma<<<256, 512, 0, stream>>>(a_row, ac_t, v_t, attn);

    gemm256<<<dim3(64, 4), 256, 0, stream>>>(attn, opw, opb, out, 4096, 1.0f);
}